// Round 4
// baseline (232.114 us; speedup 1.0000x reference)
//
#include <hip/hip_runtime.h>
#include <hip/hip_bf16.h>
#include <math.h>

#define HW    3136
#define WIMG  56
#define NPIX  25088   // 8 * 3136
#define CIN   128
#define RED   32
#define NGROUP 8
#define GCH   16
#define KKK   49

typedef __attribute__((ext_vector_type(8))) short short8;
typedef __attribute__((ext_vector_type(4))) float f32x4;
typedef unsigned short ushort_t;

static __device__ __forceinline__ ushort_t f2b(float f) {
    union { __hip_bfloat16 b; unsigned short u; } cv;
    cv.b = __float2bfloat16(f);
    return cv.u;
}

// ---------------- weight fp32 -> bf16 conversion (w1: 65536, w2: 65536) ----------------
__global__ __launch_bounds__(256) void k_wcvt(const float* __restrict__ w1,
    const float* __restrict__ w2, ushort_t* __restrict__ w1b, ushort_t* __restrict__ w2b)
{
    int i = blockIdx.x * 256 + threadIdx.x;
    if (i < 65536) w1b[i] = f2b(w1[i]);
    else           w2b[i - 65536] = f2b(w2[i - 65536]);
}

// ---------------- K1a: conv1 (1x1) + BN(eval) + ReLU -> t (b,32,hw) fp32 ----------------
__global__ __launch_bounds__(256) void k_conv1(const float* __restrict__ x,
    const float* __restrict__ w, const float* __restrict__ bias,
    const float* __restrict__ gam, const float* __restrict__ bet,
    const float* __restrict__ mu, const float* __restrict__ var,
    float* __restrict__ t)
{
    int o4 = (blockIdx.x * 256) / NPIX;         // block-uniform
    int pg = blockIdx.x * 256 + threadIdx.x - o4 * NPIX;
    int b  = pg / HW;
    int p  = pg - b * HW;
    const float* xb = x + (size_t)b * CIN * HW + p;
    int o = o4 * 4;
    const float* w0 = w + (size_t)(o + 0) * CIN;
    const float* w1 = w + (size_t)(o + 1) * CIN;
    const float* w2 = w + (size_t)(o + 2) * CIN;
    const float* w3 = w + (size_t)(o + 3) * CIN;
    float a0 = 0.f, a1 = 0.f, a2 = 0.f, a3 = 0.f;
    #pragma unroll 8
    for (int c = 0; c < CIN; ++c) {
        float xv = xb[(size_t)c * HW];
        a0 += w0[c] * xv;
        a1 += w1[c] * xv;
        a2 += w2[c] * xv;
        a3 += w3[c] * xv;
    }
    float acc[4] = {a0, a1, a2, a3};
    #pragma unroll
    for (int i = 0; i < 4; ++i) {
        int oo = o + i;
        float v  = acc[i] + bias[oo];
        float sc = gam[oo] * rsqrtf(var[oo] + 1e-5f);
        v = (v - mu[oo]) * sc + bet[oo];
        v = fmaxf(v, 0.f);
        t[((size_t)b * RED + oo) * HW + p] = v;
    }
}

// ---------------- fused conv2 + involution, LDS x-tile -> inv (b,128,hw) fp32 ----------------
// block = (b, g, 4-row strip). LDS tile: 16 ch x 10 rows x 56 cols, stride 20 f/pixel
// (16B-aligned rows for ds_read_b128; bank stride 20 mod 32 -> <=2-way aliasing).
#define TROWS 4
#define LROWS 10          // TROWS + 6 halo
#define PSTR  20          // floats per pixel slot
__global__ __launch_bounds__(256) void k_inv_f(const float* __restrict__ x,
    const float* __restrict__ t, const float* __restrict__ w2,
    const float* __restrict__ cb, float* __restrict__ inv)
{
    __shared__ float sx[LROWS * WIMG * PSTR];   // 44.8 KB
    int bid = blockIdx.x;
    int rt = bid % 14;              // row tile
    int g  = (bid / 14) & 7;        // group
    int b  = bid / 112;             // image
    int r0 = rt * TROWS;
    const float* xg = x + ((size_t)b * CIN + g * GCH) * HW;

    // ---- stage x tile (zero-fill vertical OOB) ----
    for (int i = threadIdx.x; i < GCH * LROWS * WIMG; i += 256) {
        int cc  = i / (LROWS * WIMG);
        int rem = i - cc * (LROWS * WIMG);
        int row = rem / WIMG;
        int col = rem - row * WIMG;
        int grow = r0 - 3 + row;
        float v = (grow >= 0 && grow < WIMG) ? xg[(size_t)cc * HW + grow * WIMG + col] : 0.f;
        sx[(row * WIMG + col) * PSTR + cc] = v;
    }
    __syncthreads();

    int tid = threadIdx.x;
    if (tid >= TROWS * WIMG) return;
    int row = tid / WIMG;
    int col = tid - row * WIMG;
    int p   = (r0 + row) * WIMG + col;

    const float* tb = t + (size_t)b * RED * HW + p;
    float tv[RED];
    #pragma unroll
    for (int j = 0; j < RED; ++j) tv[j] = tb[(size_t)j * HW];

    const float* w2g = w2 + (size_t)g * KKK * RED;   // block-uniform -> s_loads
    const float* cbg = cb + g * KKK;

    float acc[GCH];
    #pragma unroll
    for (int cc = 0; cc < GCH; ++cc) acc[cc] = 0.f;

    #pragma unroll 7
    for (int k = 0; k < KKK; ++k) {
        int ky = k / 7;
        int dy = ky - 3;
        int dx = (k - ky * 7) - 3;
        // dynamic kernel weight
        const float* wr = w2g + k * RED;
        float wk = cbg[k];
        #pragma unroll
        for (int j = 0; j < RED; ++j) wk += wr[j] * tv[j];
        // horizontal clamp, zero weight when OOB (vertical OOB rows are zero in LDS)
        int xx = col + dx;
        int xxc = min(max(xx, 0), WIMG - 1);
        wk = (xx == xxc) ? wk : 0.f;
        const float* sp = &sx[((row + dy + 3) * WIMG + xxc) * PSTR];
        #pragma unroll
        for (int q = 0; q < 4; ++q) {
            f32x4 v = *(const f32x4*)(sp + q * 4);    // ds_read_b128
            acc[q * 4 + 0] += wk * v[0];
            acc[q * 4 + 1] += wk * v[1];
            acc[q * 4 + 2] += wk * v[2];
            acc[q * 4 + 3] += wk * v[3];
        }
    }
    float* ob = inv + ((size_t)b * CIN + g * GCH) * HW + p;
    #pragma unroll
    for (int cc = 0; cc < GCH; ++cc) ob[(size_t)cc * HW] = acc[cc];
}

// ---------------- K2: LayerNorm -> y (npix,128) bf16 channels-last ----------------
__global__ __launch_bounds__(256) void k_ln(const float* __restrict__ inv,
    const float* __restrict__ lnw, const float* __restrict__ lnb,
    ushort_t* __restrict__ yb)
{
    int id = blockIdx.x * 256 + threadIdx.x;   // global pixel
    int b  = id / HW;
    int p  = id - b * HW;
    const float* ib = inv + (size_t)b * CIN * HW + p;
    float s = 0.f, s2 = 0.f;
    #pragma unroll 8
    for (int c = 0; c < CIN; ++c) {
        float v = ib[(size_t)c * HW];
        s += v; s2 += v * v;
    }
    float m    = s  * (1.0f / CIN);
    float vr   = s2 * (1.0f / CIN) - m * m;
    float rstd = rsqrtf(vr + 1e-6f);
    ushort_t* yr = yb + (size_t)id * CIN;
    #pragma unroll
    for (int c8 = 0; c8 < CIN / 8; ++c8) {
        unsigned int pk[4];
        #pragma unroll
        for (int h = 0; h < 4; ++h) {
            int c = c8 * 8 + h * 2;
            float v0 = (ib[(size_t)c * HW] - m) * rstd * lnw[c] + lnb[c];
            float v1 = (ib[(size_t)(c + 1) * HW] - m) * rstd * lnw[c + 1] + lnb[c + 1];
            pk[h] = (unsigned int)f2b(v0) | ((unsigned int)f2b(v1) << 16);
        }
        *(uint4*)&yr[c8 * 8] = make_uint4(pk[0], pk[1], pk[2], pk[3]);
    }
}

// ---------------- MFMA GEMM: C[M x N] = A[M x KD] (bf16) * B[N x KD]^T (bf16) ----------------
// BN = 128, waves 2x2. BM in {64,128}. TM = BM/32, TN = 4.
// EPI 0: +bias(fp32), exact GELU, store bf16 row-major (stride 512) to Cb
// EPI 1: +bias(fp32), +residual x (fp32 channels-first), store fp32 channels-first to Cf
template<int KD, int BM, int TM, int EPI>
__global__ __launch_bounds__(256) void k_gemm(const ushort_t* __restrict__ A,
    const ushort_t* __restrict__ B, const float* __restrict__ bias,
    const float* __restrict__ xres, ushort_t* __restrict__ Cb, float* __restrict__ Cf)
{
    constexpr int TN = 4;
    constexpr int APASS = BM / 64;
    __shared__ short sA[BM * 40];      // [row][40], 16B-aligned rows, <=2-way bank alias
    __shared__ short sB[128 * 40];
    int tid  = threadIdx.x;
    int lane = tid & 63;
    int wv   = tid >> 6;
    int wm   = wv & 1, wn = wv >> 1;
    int ln15 = lane & 15, quad = lane >> 4;
    int lr = tid >> 2, lc = tid & 3;          // staging: row / 16B-chunk
    int p0 = blockIdx.x * BM, j0 = blockIdx.y * 128;

    f32x4 acc[TM][TN];
    #pragma unroll
    for (int i = 0; i < TM; ++i)
        #pragma unroll
        for (int j = 0; j < TN; ++j) acc[i][j] = (f32x4)0.f;

    uint4 ga[APASS], gb[2];
    #pragma unroll
    for (int a = 0; a < APASS; ++a)
        ga[a] = *(const uint4*)&A[(size_t)(p0 + a * 64 + lr) * KD + lc * 8];
    #pragma unroll
    for (int bpass = 0; bpass < 2; ++bpass)
        gb[bpass] = *(const uint4*)&B[(size_t)(j0 + bpass * 64 + lr) * KD + lc * 8];

    for (int kc = 0; kc < KD; kc += 32) {
        __syncthreads();
        #pragma unroll
        for (int a = 0; a < APASS; ++a)
            *(uint4*)&sA[(a * 64 + lr) * 40 + lc * 8] = ga[a];
        #pragma unroll
        for (int bpass = 0; bpass < 2; ++bpass)
            *(uint4*)&sB[(bpass * 64 + lr) * 40 + lc * 8] = gb[bpass];
        __syncthreads();
        if (kc + 32 < KD) {
            #pragma unroll
            for (int a = 0; a < APASS; ++a)
                ga[a] = *(const uint4*)&A[(size_t)(p0 + a * 64 + lr) * KD + kc + 32 + lc * 8];
            #pragma unroll
            for (int bpass = 0; bpass < 2; ++bpass)
                gb[bpass] = *(const uint4*)&B[(size_t)(j0 + bpass * 64 + lr) * KD + kc + 32 + lc * 8];
        }
        short8 af[TM], bf[TN];
        #pragma unroll
        for (int tm = 0; tm < TM; ++tm)
            af[tm] = *(const short8*)&sA[(wm * (BM / 2) + tm * 16 + ln15) * 40 + quad * 8];
        #pragma unroll
        for (int tn = 0; tn < TN; ++tn)
            bf[tn] = *(const short8*)&sB[(wn * 64 + tn * 16 + ln15) * 40 + quad * 8];
        #pragma unroll
        for (int tm = 0; tm < TM; ++tm)
            #pragma unroll
            for (int tn = 0; tn < TN; ++tn)
                acc[tm][tn] = __builtin_amdgcn_mfma_f32_16x16x32_bf16(af[tm], bf[tn], acc[tm][tn], 0, 0, 0);
    }

    if (EPI == 0) {
        #pragma unroll
        for (int tm = 0; tm < TM; ++tm) {
            int mbase = p0 + wm * (BM / 2) + tm * 16 + quad * 4;
            #pragma unroll
            for (int tn = 0; tn < TN; ++tn) {
                int n = j0 + wn * 64 + tn * 16 + ln15;
                float bj = bias[n];
                #pragma unroll
                for (int r = 0; r < 4; ++r) {
                    float h = acc[tm][tn][r] + bj;
                    float gv = 0.5f * h * (1.f + erff(h * 0.70710678118654752f));
                    Cb[(size_t)(mbase + r) * 512 + n] = f2b(gv);
                }
            }
        }
    } else {
        #pragma unroll
        for (int tm = 0; tm < TM; ++tm) {
            int mg = p0 + wm * (BM / 2) + tm * 16 + quad * 4;  // global pixel, %4==0
            int b  = mg / HW;
            int p  = mg - b * HW;
            #pragma unroll
            for (int tn = 0; tn < TN; ++tn) {
                int c = j0 + wn * 64 + tn * 16 + ln15;
                size_t base = ((size_t)b * CIN + c) * HW + p;
                float bj = bias[c];
                float4 rv = *(const float4*)&xres[base];
                float4 ov = make_float4(acc[tm][tn][0] + bj + rv.x,
                                        acc[tm][tn][1] + bj + rv.y,
                                        acc[tm][tn][2] + bj + rv.z,
                                        acc[tm][tn][3] + bj + rv.w);
                *(float4*)&Cf[base] = ov;
            }
        }
    }
}

extern "C" void kernel_launch(void* const* d_in, const int* in_sizes, int n_in,
                              void* d_out, int out_size, void* d_ws, size_t ws_size,
                              hipStream_t stream) {
    const float* x       = (const float*)d_in[0];
    const float* conv1_w = (const float*)d_in[1];
    const float* conv1_b = (const float*)d_in[2];
    const float* bn_g    = (const float*)d_in[3];
    const float* bn_b    = (const float*)d_in[4];
    const float* bn_m    = (const float*)d_in[5];
    const float* bn_v    = (const float*)d_in[6];
    const float* conv2_w = (const float*)d_in[7];
    const float* conv2_b = (const float*)d_in[8];
    const float* ln_w    = (const float*)d_in[9];
    const float* ln_b    = (const float*)d_in[10];
    const float* w1      = (const float*)d_in[11];
    const float* b1      = (const float*)d_in[12];
    const float* w2      = (const float*)d_in[13];
    const float* b2      = (const float*)d_in[14];
    float* out = (float*)d_out;

    float* ws   = (float*)d_ws;
    float* t    = ws;                                  // 802,816 f   (3.2 MB)
    float* inv  = t + 802816;                          // 3,211,264 f (12.8 MB)
    ushort_t* yb  = (ushort_t*)(inv + 3211264);        // 3,211,264 us (6.4 MB)
    ushort_t* hb  = yb + (size_t)NPIX * CIN;           // 12,845,056 us (25.7 MB)
    ushort_t* w1b = hb + (size_t)NPIX * 512;           // 65,536 us
    ushort_t* w2b = w1b + 65536;                       // 65,536 us

    k_wcvt <<<512, 256, 0, stream>>>(w1, w2, w1b, w2b);
    k_conv1<<<784, 256, 0, stream>>>(x, conv1_w, conv1_b, bn_g, bn_b, bn_m, bn_v, t);
    k_inv_f<<<896, 256, 0, stream>>>(x, t, conv2_w, conv2_b, inv);
    k_ln   <<<98, 256, 0, stream>>>(inv, ln_w, ln_b, yb);
    k_gemm<128, 128, 4, 0><<<dim3(196, 4), 256, 0, stream>>>(yb, w1b, b1, nullptr, hb, nullptr);
    k_gemm<512, 64, 2, 1><<<dim3(392, 1), 256, 0, stream>>>(hb, w2b, b2, x, nullptr, out);
}

// Round 5
// 220.890 us; speedup vs baseline: 1.0508x; 1.0508x over previous
//
#include <hip/hip_runtime.h>
#include <hip/hip_bf16.h>
#include <math.h>

#define HW    3136
#define WIMG  56
#define NPIX  25088   // 8 * 3136
#define CIN   128
#define RED   32
#define NGROUP 8
#define GCH   16
#define KKK   49

typedef __attribute__((ext_vector_type(8))) short short8;
typedef __attribute__((ext_vector_type(4))) float f32x4;
typedef unsigned short ushort_t;

static __device__ __forceinline__ unsigned int f2b(float f) {
    union { __hip_bfloat16 b; unsigned short u; } cv;
    cv.b = __float2bfloat16(f);
    return (unsigned int)cv.u;
}

// ---------------- k_prep: weight conversions ----------------
// w2b[128*512] = bf16(w2); lw1b[512*128] = bf16(w1 * ln_w[c]);
// c1b[32*128] = bf16(conv1_w); c2b[400*32] = bf16(conv2_w) zero-padded rows 392..399;
// sc1/sh1[32]: folded BN affine.
__global__ __launch_bounds__(256) void k_prep(const float* __restrict__ conv1_w,
    const float* __restrict__ conv1_b, const float* __restrict__ bn_g,
    const float* __restrict__ bn_b, const float* __restrict__ bn_m,
    const float* __restrict__ bn_v, const float* __restrict__ conv2_w,
    const float* __restrict__ ln_w, const float* __restrict__ w1,
    const float* __restrict__ w2,
    ushort_t* __restrict__ c1b, ushort_t* __restrict__ c2b,
    ushort_t* __restrict__ lw1b, ushort_t* __restrict__ w2b,
    float* __restrict__ sc1, float* __restrict__ sh1)
{
    int id = blockIdx.x * 256 + threadIdx.x;     // 0..65535
    w2b[id] = (ushort_t)f2b(w2[id]);
    int c = id & 127;
    lw1b[id] = (ushort_t)f2b(w1[id] * ln_w[c]);
    if (id < 4096)  c1b[id] = (ushort_t)f2b(conv1_w[id]);
    if (id < 12800) c2b[id] = (id < 12544) ? (ushort_t)f2b(conv2_w[id]) : (ushort_t)0;
    if (id < 32) {
        float sc = bn_g[id] * rsqrtf(bn_v[id] + 1e-5f);
        sc1[id] = sc;
        sh1[id] = (conv1_b[id] - bn_m[id]) * sc + bn_b[id];
    }
}

// s1[n] = sum_c ln_w[c]*w1[n,c]; t1[n] = sum_c ln_b[c]*w1[n,c]  (fp32)
__global__ void k_prep2(const float* __restrict__ w1, const float* __restrict__ ln_w,
    const float* __restrict__ ln_b, float* __restrict__ s1, float* __restrict__ t1)
{
    int n = threadIdx.x;   // 512
    const float* wr = w1 + (size_t)n * 128;
    float s = 0.f, t = 0.f;
    #pragma unroll 8
    for (int c = 0; c < 128; ++c) { float w = wr[c]; s += ln_w[c] * w; t += ln_b[c] * w; }
    s1[n] = s; t1[n] = t;
}

// ---------------- k_dw: fused conv1+BN+ReLU+conv2 (MFMA) -> wgtT[gk][P] bf16 ----------------
// Block = 64 pixels. Stage x transposed to LDS [p][c] bf16. Stage1: t = relu(bn(x.W1c)),
// per-wave 16-pixel m-tile, kept in LDS. Stage2: wgt = t.W2c^T + b, K=32 single MFMA.
__global__ __launch_bounds__(256) void k_dw(const float* __restrict__ x,
    const short* __restrict__ c1b, const short* __restrict__ c2b,
    const float* __restrict__ sc1, const float* __restrict__ sh1,
    const float* __restrict__ c2bias, ushort_t* __restrict__ wgtT)
{
    __shared__ short sxa[64 * 136];   // [p][c], stride 136 (16B-aligned rows)
    __shared__ short st[64 * 40];     // [p][o], stride 40
    int tid = threadIdx.x;
    int P0 = blockIdx.x * 64;
    int b  = P0 / HW;                 // block-uniform (HW % 64 == 0)
    int p0 = P0 - b * HW;
    const float* xb = x + (size_t)b * CIN * HW + p0;
    #pragma unroll
    for (int it = 0; it < 32; ++it) {
        int idx = it * 256 + tid;
        int c = idx >> 6, pp = idx & 63;
        sxa[pp * 136 + c] = (short)f2b(xb[(size_t)c * HW + pp]);
    }
    __syncthreads();
    int lane = tid & 63, wv = tid >> 6;
    int ln15 = lane & 15, quad = lane >> 4;

    // ---- stage 1: t[64p x 32o], wave wv owns m-tile wv ----
    f32x4 acc1[2] = {(f32x4)0.f, (f32x4)0.f};
    #pragma unroll
    for (int kc = 0; kc < 128; kc += 32) {
        short8 af = *(const short8*)&sxa[(wv * 16 + ln15) * 136 + kc + quad * 8];
        #pragma unroll
        for (int nt = 0; nt < 2; ++nt) {
            short8 bf = *(const short8*)&c1b[(size_t)(nt * 16 + ln15) * 128 + kc + quad * 8];
            acc1[nt] = __builtin_amdgcn_mfma_f32_16x16x32_bf16(af, bf, acc1[nt], 0, 0, 0);
        }
    }
    #pragma unroll
    for (int nt = 0; nt < 2; ++nt) {
        int o = nt * 16 + ln15;
        float sc = sc1[o], sh = sh1[o];
        #pragma unroll
        for (int r = 0; r < 4; ++r) {
            float tv = fmaxf(acc1[nt][r] * sc + sh, 0.f);
            st[(wv * 16 + quad * 4 + r) * 40 + o] = (short)f2b(tv);
        }
    }
    // wave wrote & reads only its own 16 rows -> no barrier needed
    short8 af2 = *(const short8*)&st[(wv * 16 + ln15) * 40 + quad * 8];
    f32x4 zc = (f32x4)0.f;
    #pragma unroll
    for (int nt = 0; nt < 25; ++nt) {
        int gk = nt * 16 + ln15;
        short8 bf2 = *(const short8*)&c2b[(size_t)gk * 32 + quad * 8];
        f32x4 a2 = __builtin_amdgcn_mfma_f32_16x16x32_bf16(af2, bf2, zc, 0, 0, 0);
        if (gk < 392) {
            float bj = c2bias[gk];
            uint2 pk;
            pk.x = f2b(a2[0] + bj) | (f2b(a2[1] + bj) << 16);
            pk.y = f2b(a2[2] + bj) | (f2b(a2[3] + bj) << 16);
            *(uint2*)&wgtT[(size_t)gk * NPIX + P0 + wv * 16 + quad * 4] = pk;
        }
    }
}

// ---------------- k_inv: involution gather -> invb[P][128] bf16 + LN stats ----------------
// thread = (group, half, 4 consecutive pixels). grid (98, 16), block 64.
__global__ __launch_bounds__(64) void k_inv(const float* __restrict__ x,
    const ushort_t* __restrict__ wgtT, ushort_t* __restrict__ invb,
    float* __restrict__ ssum, float* __restrict__ ssq)
{
    int q   = blockIdx.x * 64 + threadIdx.x;   // pixel quad 0..6271
    int P0  = q * 4;
    int g   = blockIdx.y >> 1;
    int sub = blockIdx.y & 1;
    int b   = P0 / HW;
    int p   = P0 - b * HW;
    int prow = p / WIMG;
    int pcol = p - prow * WIMG;                // multiple of 4
    const float* xc = x + ((size_t)b * CIN + g * GCH + sub * 8) * HW;
    const ushort_t* wg = wgtT + (size_t)g * KKK * NPIX + P0;
    float acc[4][8];
    #pragma unroll
    for (int i = 0; i < 4; ++i)
        #pragma unroll
        for (int c = 0; c < 8; ++c) acc[i][c] = 0.f;
    bool c_lo = (pcol >= 4);
    bool c_hi = (pcol <= 48);
    #pragma unroll
    for (int dy = -3; dy <= 3; ++dy) {
        int grow = prow + dy;
        if (grow < 0 || grow >= WIMG) continue;
        float wkf[7][4];
        #pragma unroll
        for (int dx = 0; dx < 7; ++dx) {
            uint2 wld = *(const uint2*)&wg[(size_t)((dy + 3) * 7 + dx) * NPIX];
            wkf[dx][0] = __uint_as_float(wld.x << 16);
            wkf[dx][1] = __uint_as_float(wld.x & 0xffff0000u);
            wkf[dx][2] = __uint_as_float(wld.y << 16);
            wkf[dx][3] = __uint_as_float(wld.y & 0xffff0000u);
        }
        const float* xrow = xc + grow * WIMG + pcol;
        #pragma unroll
        for (int c = 0; c < 8; ++c) {
            const float* xr = xrow + (size_t)c * HW;
            float4 v0 = c_lo ? *(const float4*)(xr - 4) : make_float4(0.f,0.f,0.f,0.f);
            float4 v1 = *(const float4*)(xr);
            float4 v2 = c_hi ? *(const float4*)(xr + 4) : make_float4(0.f,0.f,0.f,0.f);
            float vv[12] = {v0.x,v0.y,v0.z,v0.w, v1.x,v1.y,v1.z,v1.w, v2.x,v2.y,v2.z,v2.w};
            #pragma unroll
            for (int dx = 0; dx < 7; ++dx)
                #pragma unroll
                for (int i = 0; i < 4; ++i)
                    acc[i][c] += wkf[dx][i] * vv[i + dx + 1];
        }
    }
    #pragma unroll
    for (int i = 0; i < 4; ++i) {
        unsigned pk[4];
        float s = 0.f, s2 = 0.f;
        #pragma unroll
        for (int h = 0; h < 4; ++h)
            pk[h] = f2b(acc[i][2*h]) | (f2b(acc[i][2*h+1]) << 16);
        #pragma unroll
        for (int c = 0; c < 8; ++c) { s += acc[i][c]; s2 += acc[i][c] * acc[i][c]; }
        *(uint4*)&invb[(size_t)(P0 + i) * CIN + g * GCH + sub * 8] = make_uint4(pk[0],pk[1],pk[2],pk[3]);
        atomicAdd(&ssum[P0 + i], s);
        atomicAdd(&ssq[P0 + i], s2);
    }
}

// ---------------- GEMM1 (LN fused): hb = GELU(rstd*(inv.lw1^T - mu*s1) + t1 + b1) ----------------
// BM=128, BN=128, K=128. grid (196, 4).
__global__ __launch_bounds__(256) void k_gemm1(const ushort_t* __restrict__ A,
    const ushort_t* __restrict__ B, const float* __restrict__ ssum,
    const float* __restrict__ ssq, const float* __restrict__ s1,
    const float* __restrict__ t1, const float* __restrict__ b1,
    ushort_t* __restrict__ Cb)
{
    __shared__ short sA[128 * 40];
    __shared__ short sB[128 * 40];
    int tid  = threadIdx.x;
    int lane = tid & 63;
    int wv   = tid >> 6;
    int wm   = wv & 1, wn = wv >> 1;
    int ln15 = lane & 15, quad = lane >> 4;
    int lr = tid >> 2, lc = tid & 3;
    int p0 = blockIdx.x * 128, j0 = blockIdx.y * 128;

    f32x4 acc[4][4];
    #pragma unroll
    for (int i = 0; i < 4; ++i)
        #pragma unroll
        for (int j = 0; j < 4; ++j) acc[i][j] = (f32x4)0.f;

    uint4 ga[2], gb[2];
    #pragma unroll
    for (int a = 0; a < 2; ++a)
        ga[a] = *(const uint4*)&A[(size_t)(p0 + a * 64 + lr) * 128 + lc * 8];
    #pragma unroll
    for (int bp = 0; bp < 2; ++bp)
        gb[bp] = *(const uint4*)&B[(size_t)(j0 + bp * 64 + lr) * 128 + lc * 8];

    for (int kc = 0; kc < 128; kc += 32) {
        __syncthreads();
        #pragma unroll
        for (int a = 0; a < 2; ++a) *(uint4*)&sA[(a * 64 + lr) * 40 + lc * 8] = ga[a];
        #pragma unroll
        for (int bp = 0; bp < 2; ++bp) *(uint4*)&sB[(bp * 64 + lr) * 40 + lc * 8] = gb[bp];
        __syncthreads();
        if (kc + 32 < 128) {
            #pragma unroll
            for (int a = 0; a < 2; ++a)
                ga[a] = *(const uint4*)&A[(size_t)(p0 + a * 64 + lr) * 128 + kc + 32 + lc * 8];
            #pragma unroll
            for (int bp = 0; bp < 2; ++bp)
                gb[bp] = *(const uint4*)&B[(size_t)(j0 + bp * 64 + lr) * 128 + kc + 32 + lc * 8];
        }
        short8 af[4], bf[4];
        #pragma unroll
        for (int tm = 0; tm < 4; ++tm)
            af[tm] = *(const short8*)&sA[(wm * 64 + tm * 16 + ln15) * 40 + quad * 8];
        #pragma unroll
        for (int tn = 0; tn < 4; ++tn)
            bf[tn] = *(const short8*)&sB[(wn * 64 + tn * 16 + ln15) * 40 + quad * 8];
        #pragma unroll
        for (int tm = 0; tm < 4; ++tm)
            #pragma unroll
            for (int tn = 0; tn < 4; ++tn)
                acc[tm][tn] = __builtin_amdgcn_mfma_f32_16x16x32_bf16(af[tm], bf[tn], acc[tm][tn], 0, 0, 0);
    }

    #pragma unroll
    for (int tm = 0; tm < 4; ++tm) {
        int mbase = p0 + wm * 64 + tm * 16 + quad * 4;
        float mu_r[4], rs_r[4];
        #pragma unroll
        for (int r = 0; r < 4; ++r) {
            int m = mbase + r;
            float muv = ssum[m] * (1.f / 128.f);
            float varv = ssq[m] * (1.f / 128.f) - muv * muv;
            mu_r[r] = muv;
            rs_r[r] = rsqrtf(varv + 1e-6f);
        }
        #pragma unroll
        for (int tn = 0; tn < 4; ++tn) {
            int n = j0 + wn * 64 + tn * 16 + ln15;
            float s1n = s1[n];
            float t1n = t1[n] + b1[n];
            #pragma unroll
            for (int r = 0; r < 4; ++r) {
                float h = rs_r[r] * (acc[tm][tn][r] - mu_r[r] * s1n) + t1n;
                float gv = 0.5f * h * (1.f + erff(h * 0.70710678118654752f));
                Cb[(size_t)(mbase + r) * 512 + n] = (ushort_t)f2b(gv);
            }
        }
    }
}

// ---------------- GEMM2: out = hb.w2^T + b2 + x (fp32 channels-first) ----------------
// BM=64, BN=128, K=512. grid (392, 1).
__global__ __launch_bounds__(256) void k_gemm2(const ushort_t* __restrict__ A,
    const ushort_t* __restrict__ B, const float* __restrict__ bias,
    const float* __restrict__ xres, float* __restrict__ Cf)
{
    __shared__ short sA[64 * 40];
    __shared__ short sB[128 * 40];
    int tid  = threadIdx.x;
    int lane = tid & 63;
    int wv   = tid >> 6;
    int wm   = wv & 1, wn = wv >> 1;
    int ln15 = lane & 15, quad = lane >> 4;
    int lr = tid >> 2, lc = tid & 3;
    int p0 = blockIdx.x * 64, j0 = 0;

    f32x4 acc[2][4];
    #pragma unroll
    for (int i = 0; i < 2; ++i)
        #pragma unroll
        for (int j = 0; j < 4; ++j) acc[i][j] = (f32x4)0.f;

    uint4 ga, gb[2];
    ga = *(const uint4*)&A[(size_t)(p0 + lr) * 512 + lc * 8];
    #pragma unroll
    for (int bp = 0; bp < 2; ++bp)
        gb[bp] = *(const uint4*)&B[(size_t)(j0 + bp * 64 + lr) * 512 + lc * 8];

    for (int kc = 0; kc < 512; kc += 32) {
        __syncthreads();
        *(uint4*)&sA[lr * 40 + lc * 8] = ga;
        #pragma unroll
        for (int bp = 0; bp < 2; ++bp) *(uint4*)&sB[(bp * 64 + lr) * 40 + lc * 8] = gb[bp];
        __syncthreads();
        if (kc + 32 < 512) {
            ga = *(const uint4*)&A[(size_t)(p0 + lr) * 512 + kc + 32 + lc * 8];
            #pragma unroll
            for (int bp = 0; bp < 2; ++bp)
                gb[bp] = *(const uint4*)&B[(size_t)(j0 + bp * 64 + lr) * 512 + kc + 32 + lc * 8];
        }
        short8 af[2], bf[4];
        #pragma unroll
        for (int tm = 0; tm < 2; ++tm)
            af[tm] = *(const short8*)&sA[(wm * 32 + tm * 16 + ln15) * 40 + quad * 8];
        #pragma unroll
        for (int tn = 0; tn < 4; ++tn)
            bf[tn] = *(const short8*)&sB[(wn * 64 + tn * 16 + ln15) * 40 + quad * 8];
        #pragma unroll
        for (int tm = 0; tm < 2; ++tm)
            #pragma unroll
            for (int tn = 0; tn < 4; ++tn)
                acc[tm][tn] = __builtin_amdgcn_mfma_f32_16x16x32_bf16(af[tm], bf[tn], acc[tm][tn], 0, 0, 0);
    }

    #pragma unroll
    for (int tm = 0; tm < 2; ++tm) {
        int mg = p0 + wm * 32 + tm * 16 + quad * 4;
        int b  = mg / HW;
        int p  = mg - b * HW;
        #pragma unroll
        for (int tn = 0; tn < 4; ++tn) {
            int c = j0 + wn * 64 + tn * 16 + ln15;
            size_t base = ((size_t)b * CIN + c) * HW + p;
            float bj = bias[c];
            float4 rv = *(const float4*)&xres[base];
            float4 ov = make_float4(acc[tm][tn][0] + bj + rv.x,
                                    acc[tm][tn][1] + bj + rv.y,
                                    acc[tm][tn][2] + bj + rv.z,
                                    acc[tm][tn][3] + bj + rv.w);
            *(float4*)&Cf[base] = ov;
        }
    }
}

extern "C" void kernel_launch(void* const* d_in, const int* in_sizes, int n_in,
                              void* d_out, int out_size, void* d_ws, size_t ws_size,
                              hipStream_t stream) {
    const float* x       = (const float*)d_in[0];
    const float* conv1_w = (const float*)d_in[1];
    const float* conv1_b = (const float*)d_in[2];
    const float* bn_g    = (const float*)d_in[3];
    const float* bn_b    = (const float*)d_in[4];
    const float* bn_m    = (const float*)d_in[5];
    const float* bn_v    = (const float*)d_in[6];
    const float* conv2_w = (const float*)d_in[7];
    const float* conv2_b = (const float*)d_in[8];
    const float* ln_w    = (const float*)d_in[9];
    const float* ln_b    = (const float*)d_in[10];
    const float* w1      = (const float*)d_in[11];
    const float* b1      = (const float*)d_in[12];
    const float* w2      = (const float*)d_in[13];
    const float* b2      = (const float*)d_in[14];
    float* out = (float*)d_out;

    float* F = (float*)d_ws;
    float* ssum = F;                 // 25088
    float* ssq  = F + 25088;         // 25088
    float* sc1  = F + 50176;         // 32
    float* sh1  = F + 50208;         // 32
    float* s1   = F + 50240;         // 512
    float* t1   = F + 50752;         // 512
    ushort_t* S    = (ushort_t*)(F + 51264);
    ushort_t* wgtT = S;                       // 392*25088 = 9,834,496
    ushort_t* invb = S + 9834496;             // 25088*128 = 3,211,264
    ushort_t* hb   = invb + 3211264;          // 25088*512 = 12,845,056
    ushort_t* c1b  = hb + 12845056;           // 4096
    ushort_t* c2b  = c1b + 4096;              // 12800 (400x32, padded)
    ushort_t* lw1b = c2b + 12800;             // 65536
    ushort_t* w2b  = lw1b + 65536;            // 65536

    hipMemsetAsync((void*)ssum, 0, 2 * 25088 * sizeof(float), stream);
    k_prep <<<256, 256, 0, stream>>>(conv1_w, conv1_b, bn_g, bn_b, bn_m, bn_v,
                                     conv2_w, ln_w, w1, w2, c1b, c2b, lw1b, w2b, sc1, sh1);
    k_prep2<<<1, 512, 0, stream>>>(w1, ln_w, ln_b, s1, t1);
    k_dw   <<<392, 256, 0, stream>>>(x, (const short*)c1b, (const short*)c2b,
                                     sc1, sh1, conv2_b, wgtT);
    k_inv  <<<dim3(98, 16), 64, 0, stream>>>(x, wgtT, invb, ssum, ssq);
    k_gemm1<<<dim3(196, 4), 256, 0, stream>>>(invb, lw1b, ssum, ssq, s1, t1, b1, hb);
    k_gemm2<<<392, 256, 0, stream>>>(hb, w2b, b2, x, out);
}

// Round 7
// 211.159 us; speedup vs baseline: 1.0992x; 1.0461x over previous
//
#include <hip/hip_runtime.h>
#include <hip/hip_bf16.h>
#include <math.h>

#define HW    3136
#define WIMG  56
#define NPIX  25088   // 8 * 3136
#define CIN   128
#define RED   32
#define NGROUP 8
#define GCH   16
#define KKK   49

typedef __attribute__((ext_vector_type(8))) short short8;
typedef __attribute__((ext_vector_type(4))) float f32x4;
typedef unsigned short ushort_t;

static __device__ __forceinline__ unsigned int f2b(float f) {
    union { __hip_bfloat16 b; unsigned short u; } cv;
    cv.b = __float2bfloat16(f);
    return (unsigned int)cv.u;
}

// tanh-form GELU: h*sigmoid(2z), z = 0.79788456*h*(1+0.044715 h^2); max |err| ~3e-3
static __device__ __forceinline__ float gelu_t(float h) {
    float z = h * fmaf(0.0356774081f, h * h, 0.7978845608f);
    float e = __expf(-2.f * z);
    return __fdividef(h, 1.f + e);
}

// ---------------- k_prep: weight conversions ----------------
__global__ __launch_bounds__(256) void k_prep(const float* __restrict__ conv1_w,
    const float* __restrict__ conv1_b, const float* __restrict__ bn_g,
    const float* __restrict__ bn_b, const float* __restrict__ bn_m,
    const float* __restrict__ bn_v, const float* __restrict__ conv2_w,
    const float* __restrict__ ln_w, const float* __restrict__ w1,
    const float* __restrict__ w2,
    ushort_t* __restrict__ c1b, ushort_t* __restrict__ c2b,
    ushort_t* __restrict__ lw1b, ushort_t* __restrict__ w2b,
    float* __restrict__ sc1, float* __restrict__ sh1)
{
    int id = blockIdx.x * 256 + threadIdx.x;     // 0..65535
    w2b[id] = (ushort_t)f2b(w2[id]);
    int c = id & 127;
    lw1b[id] = (ushort_t)f2b(w1[id] * ln_w[c]);
    if (id < 4096)  c1b[id] = (ushort_t)f2b(conv1_w[id]);
    if (id < 12800) c2b[id] = (id < 12544) ? (ushort_t)f2b(conv2_w[id]) : (ushort_t)0;
    if (id < 32) {
        float sc = bn_g[id] * rsqrtf(bn_v[id] + 1e-5f);
        sc1[id] = sc;
        sh1[id] = (conv1_b[id] - bn_m[id]) * sc + bn_b[id];
    }
}

// s1[n] = sum_c ln_w[c]*w1[n,c]; t1[n] = sum_c ln_b[c]*w1[n,c] + b1[n]
__global__ void k_prep2(const float* __restrict__ w1, const float* __restrict__ ln_w,
    const float* __restrict__ ln_b, const float* __restrict__ b1,
    float* __restrict__ s1, float* __restrict__ t1)
{
    int n = threadIdx.x;   // 512
    const float* wr = w1 + (size_t)n * 128;
    float s = 0.f, t = 0.f;
    #pragma unroll 8
    for (int c = 0; c < 128; ++c) { float w = wr[c]; s += ln_w[c] * w; t += ln_b[c] * w; }
    s1[n] = s; t1[n] = t + b1[n];
}

// ---------------- k_dw: fused conv1+BN+ReLU+conv2 (MFMA) -> wgtT[gk][P] bf16 ----------------
__global__ __launch_bounds__(256) void k_dw(const float* __restrict__ x,
    const short* __restrict__ c1b, const short* __restrict__ c2b,
    const float* __restrict__ sc1, const float* __restrict__ sh1,
    const float* __restrict__ c2bias, ushort_t* __restrict__ wgtT)
{
    __shared__ short sxa[64 * 136];   // [p][c], stride 136 (16B-aligned rows)
    __shared__ short st[64 * 40];     // [p][o], stride 40
    int tid = threadIdx.x;
    int P0 = blockIdx.x * 64;
    int b  = P0 / HW;                 // block-uniform (HW % 64 == 0)
    int p0 = P0 - b * HW;
    const float* xb = x + (size_t)b * CIN * HW + p0;
    #pragma unroll
    for (int it = 0; it < 32; ++it) {
        int idx = it * 256 + tid;
        int c = idx >> 6, pp = idx & 63;
        sxa[pp * 136 + c] = (short)f2b(xb[(size_t)c * HW + pp]);
    }
    __syncthreads();
    int lane = tid & 63, wv = tid >> 6;
    int ln15 = lane & 15, quad = lane >> 4;

    f32x4 acc1[2] = {(f32x4)0.f, (f32x4)0.f};
    #pragma unroll
    for (int kc = 0; kc < 128; kc += 32) {
        short8 af = *(const short8*)&sxa[(wv * 16 + ln15) * 136 + kc + quad * 8];
        #pragma unroll
        for (int nt = 0; nt < 2; ++nt) {
            short8 bf = *(const short8*)&c1b[(size_t)(nt * 16 + ln15) * 128 + kc + quad * 8];
            acc1[nt] = __builtin_amdgcn_mfma_f32_16x16x32_bf16(af, bf, acc1[nt], 0, 0, 0);
        }
    }
    #pragma unroll
    for (int nt = 0; nt < 2; ++nt) {
        int o = nt * 16 + ln15;
        float sc = sc1[o], sh = sh1[o];
        #pragma unroll
        for (int r = 0; r < 4; ++r) {
            float tv = fmaxf(acc1[nt][r] * sc + sh, 0.f);
            st[(wv * 16 + quad * 4 + r) * 40 + o] = (short)f2b(tv);
        }
    }
    short8 af2 = *(const short8*)&st[(wv * 16 + ln15) * 40 + quad * 8];
    f32x4 zc = (f32x4)0.f;
    #pragma unroll
    for (int nt = 0; nt < 25; ++nt) {
        int gk = nt * 16 + ln15;
        short8 bf2 = *(const short8*)&c2b[(size_t)gk * 32 + quad * 8];
        f32x4 a2 = __builtin_amdgcn_mfma_f32_16x16x32_bf16(af2, bf2, zc, 0, 0, 0);
        if (gk < 392) {
            float bj = c2bias[gk];
            uint2 pk;
            pk.x = f2b(a2[0] + bj) | (f2b(a2[1] + bj) << 16);
            pk.y = f2b(a2[2] + bj) | (f2b(a2[3] + bj) << 16);
            *(uint2*)&wgtT[(size_t)gk * NPIX + P0 + wv * 16 + quad * 4] = pk;
        }
    }
}

// ---------------- k_inv: involution gather -> invb[P][128] bf16 ----------------
// thread = (group, half, 4 consecutive pixels). grid 392 x 256.
__global__ __launch_bounds__(256) void k_inv(const float* __restrict__ x,
    const ushort_t* __restrict__ wgtT, ushort_t* __restrict__ invb)
{
    int id  = blockIdx.x * 256 + threadIdx.x;   // 0..100351
    int gy  = id / 6272;                        // wave-uniform (6272 % 64 == 0)
    int q   = id - gy * 6272;
    int g   = gy >> 1;
    int sub = gy & 1;
    int P0  = q * 4;
    int b   = P0 / HW;
    int p   = P0 - b * HW;
    int prow = p / WIMG;
    int pcol = p - prow * WIMG;                 // multiple of 4
    const float* xc = x + ((size_t)b * CIN + g * GCH + sub * 8) * HW;
    const ushort_t* wg = wgtT + (size_t)g * KKK * NPIX + P0;
    float acc[4][8];
    #pragma unroll
    for (int i = 0; i < 4; ++i)
        #pragma unroll
        for (int c = 0; c < 8; ++c) acc[i][c] = 0.f;
    bool c_lo = (pcol >= 4);
    bool c_hi = (pcol <= 48);
    #pragma unroll
    for (int dy = -3; dy <= 3; ++dy) {
        int grow = prow + dy;
        if (grow < 0 || grow >= WIMG) continue;
        float wkf[7][4];
        #pragma unroll
        for (int dx = 0; dx < 7; ++dx) {
            uint2 wld = *(const uint2*)&wg[(size_t)((dy + 3) * 7 + dx) * NPIX];
            wkf[dx][0] = __uint_as_float(wld.x << 16);
            wkf[dx][1] = __uint_as_float(wld.x & 0xffff0000u);
            wkf[dx][2] = __uint_as_float(wld.y << 16);
            wkf[dx][3] = __uint_as_float(wld.y & 0xffff0000u);
        }
        const float* xrow = xc + grow * WIMG + pcol;
        #pragma unroll
        for (int c = 0; c < 8; ++c) {
            const float* xr = xrow + (size_t)c * HW;
            float4 v0 = c_lo ? *(const float4*)(xr - 4) : make_float4(0.f,0.f,0.f,0.f);
            float4 v1 = *(const float4*)(xr);
            float4 v2 = c_hi ? *(const float4*)(xr + 4) : make_float4(0.f,0.f,0.f,0.f);
            float vv[12] = {v0.x,v0.y,v0.z,v0.w, v1.x,v1.y,v1.z,v1.w, v2.x,v2.y,v2.z,v2.w};
            #pragma unroll
            for (int dx = 0; dx < 7; ++dx)
                #pragma unroll
                for (int i = 0; i < 4; ++i)
                    acc[i][c] += wkf[dx][i] * vv[i + dx + 1];
        }
    }
    #pragma unroll
    for (int i = 0; i < 4; ++i) {
        unsigned pk[4];
        #pragma unroll
        for (int h = 0; h < 4; ++h)
            pk[h] = f2b(acc[i][2*h]) | (f2b(acc[i][2*h+1]) << 16);
        *(uint4*)&invb[(size_t)(P0 + i) * CIN + g * GCH + sub * 8] = make_uint4(pk[0],pk[1],pk[2],pk[3]);
    }
}

// ---------------- k_stats: per-pixel LN sums from invb ----------------
__global__ __launch_bounds__(256) void k_stats(const ushort_t* __restrict__ invb,
    float* __restrict__ ssum, float* __restrict__ ssq)
{
    int p = blockIdx.x * 256 + threadIdx.x;
    const uint4* row = (const uint4*)(invb + (size_t)p * CIN);
    float s = 0.f, s2 = 0.f;
    #pragma unroll
    for (int i = 0; i < 16; ++i) {
        uint4 v = row[i];
        unsigned u[4] = {v.x, v.y, v.z, v.w};
        #pragma unroll
        for (int j = 0; j < 4; ++j) {
            float f0 = __uint_as_float(u[j] << 16);
            float f1 = __uint_as_float(u[j] & 0xffff0000u);
            s += f0 + f1;
            s2 += f0 * f0 + f1 * f1;
        }
    }
    ssum[p] = s; ssq[p] = s2;
}

// ---------------- GEMM1 (LN fused, operand-swapped): hb[p][n] = GELU(...) ----------------
// M = hidden n (A = lw1b, 512x128), N = pixels (B = invb). grid (4, 196).
__global__ __launch_bounds__(256) void k_gemm1(const ushort_t* __restrict__ A,
    const ushort_t* __restrict__ B, const float* __restrict__ ssum,
    const float* __restrict__ ssq, const float* __restrict__ s1,
    const float* __restrict__ t1, ushort_t* __restrict__ Cb)
{
    __shared__ short sA[128 * 40];
    __shared__ short sB[128 * 40];
    int tid  = threadIdx.x;
    int lane = tid & 63;
    int wv   = tid >> 6;
    int wm   = wv & 1, wn = wv >> 1;
    int ln15 = lane & 15, quad = lane >> 4;
    int lr = tid >> 2, lc = tid & 3;
    int n0 = blockIdx.x * 128, p0 = blockIdx.y * 128;

    f32x4 acc[4][4];
    #pragma unroll
    for (int i = 0; i < 4; ++i)
        #pragma unroll
        for (int j = 0; j < 4; ++j) acc[i][j] = (f32x4)0.f;

    uint4 ga[2], gb[2];
    #pragma unroll
    for (int a = 0; a < 2; ++a)
        ga[a] = *(const uint4*)&A[(size_t)(n0 + a * 64 + lr) * 128 + lc * 8];
    #pragma unroll
    for (int bp = 0; bp < 2; ++bp)
        gb[bp] = *(const uint4*)&B[(size_t)(p0 + bp * 64 + lr) * 128 + lc * 8];

    for (int kc = 0; kc < 128; kc += 32) {
        __syncthreads();
        #pragma unroll
        for (int a = 0; a < 2; ++a) *(uint4*)&sA[(a * 64 + lr) * 40 + lc * 8] = ga[a];
        #pragma unroll
        for (int bp = 0; bp < 2; ++bp) *(uint4*)&sB[(bp * 64 + lr) * 40 + lc * 8] = gb[bp];
        __syncthreads();
        if (kc + 32 < 128) {
            #pragma unroll
            for (int a = 0; a < 2; ++a)
                ga[a] = *(const uint4*)&A[(size_t)(n0 + a * 64 + lr) * 128 + kc + 32 + lc * 8];
            #pragma unroll
            for (int bp = 0; bp < 2; ++bp)
                gb[bp] = *(const uint4*)&B[(size_t)(p0 + bp * 64 + lr) * 128 + kc + 32 + lc * 8];
        }
        short8 af[4], bf[4];
        #pragma unroll
        for (int tm = 0; tm < 4; ++tm)
            af[tm] = *(const short8*)&sA[(wm * 64 + tm * 16 + ln15) * 40 + quad * 8];
        #pragma unroll
        for (int tn = 0; tn < 4; ++tn)
            bf[tn] = *(const short8*)&sB[(wn * 64 + tn * 16 + ln15) * 40 + quad * 8];
        #pragma unroll
        for (int tm = 0; tm < 4; ++tm)
            #pragma unroll
            for (int tn = 0; tn < 4; ++tn)
                acc[tm][tn] = __builtin_amdgcn_mfma_f32_16x16x32_bf16(af[tm], bf[tn], acc[tm][tn], 0, 0, 0);
    }

    // epilogue: lane holds pixel p (col), 4 consecutive n per reg quad (row)
    #pragma unroll
    for (int tn = 0; tn < 4; ++tn) {
        int p = p0 + wn * 64 + tn * 16 + ln15;
        float muv = ssum[p] * (1.f / 128.f);
        float varv = ssq[p] * (1.f / 128.f) - muv * muv;
        float rstd = rsqrtf(varv + 1e-6f);
        #pragma unroll
        for (int tm = 0; tm < 4; ++tm) {
            int nb = n0 + wm * 64 + tm * 16 + quad * 4;
            unsigned pk[2];
            #pragma unroll
            for (int h = 0; h < 2; ++h) {
                float g0, g1;
                {
                    int n = nb + 2 * h;
                    float hh = rstd * (acc[tm][tn][2*h] - muv * s1[n]) + t1[n];
                    g0 = gelu_t(hh);
                }
                {
                    int n = nb + 2 * h + 1;
                    float hh = rstd * (acc[tm][tn][2*h+1] - muv * s1[n]) + t1[n];
                    g1 = gelu_t(hh);
                }
                pk[h] = f2b(g0) | (f2b(g1) << 16);
            }
            *(uint2*)&Cb[(size_t)p * 512 + nb] = make_uint2(pk[0], pk[1]);
        }
    }
}

// ---------------- GEMM2: out = hb.w2^T + b2 + x (fp32 channels-first) ----------------
__global__ __launch_bounds__(256) void k_gemm2(const ushort_t* __restrict__ A,
    const ushort_t* __restrict__ B, const float* __restrict__ bias,
    const float* __restrict__ xres, float* __restrict__ Cf)
{
    __shared__ short sA[64 * 40];
    __shared__ short sB[128 * 40];
    int tid  = threadIdx.x;
    int lane = tid & 63;
    int wv   = tid >> 6;
    int wm   = wv & 1, wn = wv >> 1;
    int ln15 = lane & 15, quad = lane >> 4;
    int lr = tid >> 2, lc = tid & 3;
    int p0 = blockIdx.x * 64;

    f32x4 acc[2][4];
    #pragma unroll
    for (int i = 0; i < 2; ++i)
        #pragma unroll
        for (int j = 0; j < 4; ++j) acc[i][j] = (f32x4)0.f;

    uint4 ga, gb[2];
    ga = *(const uint4*)&A[(size_t)(p0 + lr) * 512 + lc * 8];
    #pragma unroll
    for (int bp = 0; bp < 2; ++bp)
        gb[bp] = *(const uint4*)&B[(size_t)(bp * 64 + lr) * 512 + lc * 8];

    for (int kc = 0; kc < 512; kc += 32) {
        __syncthreads();
        *(uint4*)&sA[lr * 40 + lc * 8] = ga;
        #pragma unroll
        for (int bp = 0; bp < 2; ++bp) *(uint4*)&sB[(bp * 64 + lr) * 40 + lc * 8] = gb[bp];
        __syncthreads();
        if (kc + 32 < 512) {
            ga = *(const uint4*)&A[(size_t)(p0 + lr) * 512 + kc + 32 + lc * 8];
            #pragma unroll
            for (int bp = 0; bp < 2; ++bp)
                gb[bp] = *(const uint4*)&B[(size_t)(bp * 64 + lr) * 512 + kc + 32 + lc * 8];
        }
        short8 af[2], bf[4];
        #pragma unroll
        for (int tm = 0; tm < 2; ++tm)
            af[tm] = *(const short8*)&sA[(wm * 32 + tm * 16 + ln15) * 40 + quad * 8];
        #pragma unroll
        for (int tn = 0; tn < 4; ++tn)
            bf[tn] = *(const short8*)&sB[(wn * 64 + tn * 16 + ln15) * 40 + quad * 8];
        #pragma unroll
        for (int tm = 0; tm < 2; ++tm)
            #pragma unroll
            for (int tn = 0; tn < 4; ++tn)
                acc[tm][tn] = __builtin_amdgcn_mfma_f32_16x16x32_bf16(af[tm], bf[tn], acc[tm][tn], 0, 0, 0);
    }

    #pragma unroll
    for (int tm = 0; tm < 2; ++tm) {
        int mg = p0 + wm * 32 + tm * 16 + quad * 4;
        int b  = mg / HW;
        int p  = mg - b * HW;
        #pragma unroll
        for (int tn = 0; tn < 4; ++tn) {
            int c = wn * 64 + tn * 16 + ln15;
            size_t base = ((size_t)b * CIN + c) * HW + p;
            float bj = bias[c];
            float4 rv = *(const float4*)&xres[base];
            float4 ov = make_float4(acc[tm][tn][0] + bj + rv.x,
                                    acc[tm][tn][1] + bj + rv.y,
                                    acc[tm][tn][2] + bj + rv.z,
                                    acc[tm][tn][3] + bj + rv.w);
            *(float4*)&Cf[base] = ov;
        }
    }
}

extern "C" void kernel_launch(void* const* d_in, const int* in_sizes, int n_in,
                              void* d_out, int out_size, void* d_ws, size_t ws_size,
                              hipStream_t stream) {
    const float* x       = (const float*)d_in[0];
    const float* conv1_w = (const float*)d_in[1];
    const float* conv1_b = (const float*)d_in[2];
    const float* bn_g    = (const float*)d_in[3];
    const float* bn_b    = (const float*)d_in[4];
    const float* bn_m    = (const float*)d_in[5];
    const float* bn_v    = (const float*)d_in[6];
    const float* conv2_w = (const float*)d_in[7];
    const float* conv2_b = (const float*)d_in[8];
    const float* ln_w    = (const float*)d_in[9];
    const float* ln_b    = (const float*)d_in[10];
    const float* w1      = (const float*)d_in[11];
    const float* b1      = (const float*)d_in[12];
    const float* w2      = (const float*)d_in[13];
    const float* b2      = (const float*)d_in[14];
    float* out = (float*)d_out;

    float* F = (float*)d_ws;
    float* ssum = F;                 // 25088
    float* ssq  = F + 25088;         // 25088
    float* sc1  = F + 50176;         // 32
    float* sh1  = F + 50208;         // 32
    float* s1   = F + 50240;         // 512
    float* t1   = F + 50752;         // 512
    ushort_t* S    = (ushort_t*)(F + 51264);
    ushort_t* wgtT = S;                       // 392*25088 = 9,834,496
    ushort_t* invb = S + 9834496;             // 25088*128 = 3,211,264
    ushort_t* hb   = invb + 3211264;          // 25088*512 = 12,845,056
    ushort_t* c1b  = hb + 12845056;           // 4096
    ushort_t* c2b  = c1b + 4096;              // 12800 (400x32, padded)
    ushort_t* lw1b = c2b + 12800;             // 65536
    ushort_t* w2b  = lw1b + 65536;            // 65536

    k_prep <<<256, 256, 0, stream>>>(conv1_w, conv1_b, bn_g, bn_b, bn_m, bn_v,
                                     conv2_w, ln_w, w1, w2, c1b, c2b, lw1b, w2b, sc1, sh1);
    k_prep2<<<1, 512, 0, stream>>>(w1, ln_w, ln_b, b1, s1, t1);
    k_dw   <<<392, 256, 0, stream>>>(x, (const short*)c1b, (const short*)c2b,
                                     sc1, sh1, conv2_b, wgtT);
    k_inv  <<<392, 256, 0, stream>>>(x, wgtT, invb);
    k_stats<<<98, 256, 0, stream>>>(invb, ssum, ssq);
    k_gemm1<<<dim3(4, 196), 256, 0, stream>>>(lw1b, invb, ssum, ssq, s1, t1, hb);
    k_gemm2<<<392, 256, 0, stream>>>(hb, w2b, b2, x, out);
}

// Round 9
// 172.841 us; speedup vs baseline: 1.3429x; 1.2217x over previous
//
#include <hip/hip_runtime.h>
#include <hip/hip_bf16.h>
#include <math.h>

#define HW    3136
#define WIMG  56
#define NPIX  25088   // 8 * 3136
#define CIN   128
#define RED   32
#define NGROUP 8
#define GCH   16
#define KKK   49

typedef __attribute__((ext_vector_type(8))) short short8;
typedef __attribute__((ext_vector_type(4))) float f32x4;
typedef unsigned short ushort_t;

static __device__ __forceinline__ unsigned int f2b(float f) {
    union { __hip_bfloat16 b; unsigned short u; } cv;
    cv.b = __float2bfloat16(f);
    return (unsigned int)cv.u;
}

// tanh-form GELU: h*sigmoid(2z); max |err| ~3e-3 (validated: round-7 absmax 0.031)
static __device__ __forceinline__ float gelu_t(float h) {
    float z = h * fmaf(0.0356774081f, h * h, 0.7978845608f);
    float e = __expf(-2.f * z);
    return __fdividef(h, 1.f + e);
}

// ---------------- k_prep: weight conversions ----------------
__global__ __launch_bounds__(256) void k_prep(const float* __restrict__ conv1_w,
    const float* __restrict__ conv1_b, const float* __restrict__ bn_g,
    const float* __restrict__ bn_b, const float* __restrict__ bn_m,
    const float* __restrict__ bn_v, const float* __restrict__ conv2_w,
    const float* __restrict__ ln_w, const float* __restrict__ w1,
    const float* __restrict__ w2,
    ushort_t* __restrict__ c1b, ushort_t* __restrict__ c2b,
    ushort_t* __restrict__ lw1b, ushort_t* __restrict__ w2b,
    float* __restrict__ sc1, float* __restrict__ sh1)
{
    int id = blockIdx.x * 256 + threadIdx.x;     // 0..65535
    w2b[id] = (ushort_t)f2b(w2[id]);
    int c = id & 127;
    lw1b[id] = (ushort_t)f2b(w1[id] * ln_w[c]);
    if (id < 4096)  c1b[id] = (ushort_t)f2b(conv1_w[id]);
    if (id < 12800) c2b[id] = (id < 12544) ? (ushort_t)f2b(conv2_w[id]) : (ushort_t)0;
    if (id < 32) {
        float sc = bn_g[id] * rsqrtf(bn_v[id] + 1e-5f);
        sc1[id] = sc;
        sh1[id] = (conv1_b[id] - bn_m[id]) * sc + bn_b[id];
    }
}

// s1[n] = sum_c ln_w[c]*w1[n,c]; t1[n] = sum_c ln_b[c]*w1[n,c] + b1[n]
__global__ void k_prep2(const float* __restrict__ w1, const float* __restrict__ ln_w,
    const float* __restrict__ ln_b, const float* __restrict__ b1,
    float* __restrict__ s1, float* __restrict__ t1)
{
    int n = threadIdx.x;   // 512
    const float* wr = w1 + (size_t)n * 128;
    float s = 0.f, t = 0.f;
    #pragma unroll 8
    for (int c = 0; c < 128; ++c) { float w = wr[c]; s += ln_w[c] * w; t += ln_b[c] * w; }
    s1[n] = s; t1[n] = t + b1[n];
}

// ---------------- k_dw: fused conv1+BN+ReLU+conv2 (MFMA) -> wgtT[gk][P] bf16 ----------------
__global__ __launch_bounds__(256) void k_dw(const float* __restrict__ x,
    const short* __restrict__ c1b, const short* __restrict__ c2b,
    const float* __restrict__ sc1, const float* __restrict__ sh1,
    const float* __restrict__ c2bias, ushort_t* __restrict__ wgtT)
{
    __shared__ short sxa[64 * 136];   // [p][c], stride 136 (16B-aligned rows)
    __shared__ short st[64 * 40];     // [p][o], stride 40
    int tid = threadIdx.x;
    int P0 = blockIdx.x * 64;
    int b  = P0 / HW;                 // block-uniform (HW % 64 == 0)
    int p0 = P0 - b * HW;
    const float* xb = x + (size_t)b * CIN * HW + p0;
    #pragma unroll
    for (int it = 0; it < 32; ++it) {
        int idx = it * 256 + tid;
        int c = idx >> 6, pp = idx & 63;
        sxa[pp * 136 + c] = (short)f2b(xb[(size_t)c * HW + pp]);
    }
    __syncthreads();
    int lane = tid & 63, wv = tid >> 6;
    int ln15 = lane & 15, quad = lane >> 4;

    f32x4 acc1[2] = {(f32x4)0.f, (f32x4)0.f};
    #pragma unroll
    for (int kc = 0; kc < 128; kc += 32) {
        short8 af = *(const short8*)&sxa[(wv * 16 + ln15) * 136 + kc + quad * 8];
        #pragma unroll
        for (int nt = 0; nt < 2; ++nt) {
            short8 bf = *(const short8*)&c1b[(size_t)(nt * 16 + ln15) * 128 + kc + quad * 8];
            acc1[nt] = __builtin_amdgcn_mfma_f32_16x16x32_bf16(af, bf, acc1[nt], 0, 0, 0);
        }
    }
    #pragma unroll
    for (int nt = 0; nt < 2; ++nt) {
        int o = nt * 16 + ln15;
        float sc = sc1[o], sh = sh1[o];
        #pragma unroll
        for (int r = 0; r < 4; ++r) {
            float tv = fmaxf(acc1[nt][r] * sc + sh, 0.f);
            st[(wv * 16 + quad * 4 + r) * 40 + o] = (short)f2b(tv);
        }
    }
    short8 af2 = *(const short8*)&st[(wv * 16 + ln15) * 40 + quad * 8];
    f32x4 zc = (f32x4)0.f;
    #pragma unroll
    for (int nt = 0; nt < 25; ++nt) {
        int gk = nt * 16 + ln15;
        short8 bf2 = *(const short8*)&c2b[(size_t)gk * 32 + quad * 8];
        f32x4 a2 = __builtin_amdgcn_mfma_f32_16x16x32_bf16(af2, bf2, zc, 0, 0, 0);
        if (gk < 392) {
            float bj = c2bias[gk];
            uint2 pk;
            pk.x = f2b(a2[0] + bj) | (f2b(a2[1] + bj) << 16);
            pk.y = f2b(a2[2] + bj) | (f2b(a2[3] + bj) << 16);
            *(uint2*)&wgtT[(size_t)gk * NPIX + P0 + wv * 16 + quad * 4] = pk;
        }
    }
}

// ---------------- k_inv: involution gather -> invb[P][128] bf16 ----------------
__global__ __launch_bounds__(256) void k_inv(const float* __restrict__ x,
    const ushort_t* __restrict__ wgtT, ushort_t* __restrict__ invb)
{
    int id  = blockIdx.x * 256 + threadIdx.x;   // 0..100351
    int gy  = id / 6272;                        // wave-uniform (6272 % 64 == 0)
    int q   = id - gy * 6272;
    int g   = gy >> 1;
    int sub = gy & 1;
    int P0  = q * 4;
    int b   = P0 / HW;
    int p   = P0 - b * HW;
    int prow = p / WIMG;
    int pcol = p - prow * WIMG;                 // multiple of 4
    const float* xc = x + ((size_t)b * CIN + g * GCH + sub * 8) * HW;
    const ushort_t* wg = wgtT + (size_t)g * KKK * NPIX + P0;
    float acc[4][8];
    #pragma unroll
    for (int i = 0; i < 4; ++i)
        #pragma unroll
        for (int c = 0; c < 8; ++c) acc[i][c] = 0.f;
    bool c_lo = (pcol >= 4);
    bool c_hi = (pcol <= 48);
    #pragma unroll
    for (int dy = -3; dy <= 3; ++dy) {
        int grow = prow + dy;
        if (grow < 0 || grow >= WIMG) continue;
        float wkf[7][4];
        #pragma unroll
        for (int dx = 0; dx < 7; ++dx) {
            uint2 wld = *(const uint2*)&wg[(size_t)((dy + 3) * 7 + dx) * NPIX];
            wkf[dx][0] = __uint_as_float(wld.x << 16);
            wkf[dx][1] = __uint_as_float(wld.x & 0xffff0000u);
            wkf[dx][2] = __uint_as_float(wld.y << 16);
            wkf[dx][3] = __uint_as_float(wld.y & 0xffff0000u);
        }
        const float* xrow = xc + grow * WIMG + pcol;
        #pragma unroll
        for (int c = 0; c < 8; ++c) {
            const float* xr = xrow + (size_t)c * HW;
            float4 v0 = c_lo ? *(const float4*)(xr - 4) : make_float4(0.f,0.f,0.f,0.f);
            float4 v1 = *(const float4*)(xr);
            float4 v2 = c_hi ? *(const float4*)(xr + 4) : make_float4(0.f,0.f,0.f,0.f);
            float vv[12] = {v0.x,v0.y,v0.z,v0.w, v1.x,v1.y,v1.z,v1.w, v2.x,v2.y,v2.z,v2.w};
            #pragma unroll
            for (int dx = 0; dx < 7; ++dx)
                #pragma unroll
                for (int i = 0; i < 4; ++i)
                    acc[i][c] += wkf[dx][i] * vv[i + dx + 1];
        }
    }
    #pragma unroll
    for (int i = 0; i < 4; ++i) {
        unsigned pk[4];
        #pragma unroll
        for (int h = 0; h < 4; ++h)
            pk[h] = f2b(acc[i][2*h]) | (f2b(acc[i][2*h+1]) << 16);
        *(uint4*)&invb[(size_t)(P0 + i) * CIN + g * GCH + sub * 8] = make_uint4(pk[0],pk[1],pk[2],pk[3]);
    }
}

// ---------------- k_stats: per-pixel LN sums from invb ----------------
__global__ __launch_bounds__(256) void k_stats(const ushort_t* __restrict__ invb,
    float* __restrict__ ssum, float* __restrict__ ssq)
{
    int p = blockIdx.x * 256 + threadIdx.x;
    const uint4* row = (const uint4*)(invb + (size_t)p * CIN);
    float s = 0.f, s2 = 0.f;
    #pragma unroll
    for (int i = 0; i < 16; ++i) {
        uint4 v = row[i];
        unsigned u[4] = {v.x, v.y, v.z, v.w};
        #pragma unroll
        for (int j = 0; j < 4; ++j) {
            float f0 = __uint_as_float(u[j] << 16);
            float f1 = __uint_as_float(u[j] & 0xffff0000u);
            s += f0 + f1;
            s2 += f0 * f0 + f1 * f1;
        }
    }
    ssum[p] = s; ssq[p] = s2;
}

// ---------------- k_mlp: fused LN-GEMM1-GELU-GEMM2-residual ----------------
// block = 64 pixels, grid 392. Loop over 4 hidden chunks of 128:
//   phase1: H[nl][px] = MFMA(lw1 chunk [global frags], sx) + LN/GELU -> sh (LDS)
//   phase2: acc2[px][c] += MFMA(sh, w2 chunk [global frags])
__global__ __launch_bounds__(256) void k_mlp(const ushort_t* __restrict__ invb,
    const ushort_t* __restrict__ lw1b, const ushort_t* __restrict__ w2b,
    const float* __restrict__ ssum, const float* __restrict__ ssq,
    const float* __restrict__ s1, const float* __restrict__ t1,
    const float* __restrict__ b2, const float* __restrict__ xres,
    float* __restrict__ outp)
{
    __shared__ short sx[64 * 136];    // inv tile [px][c]
    __shared__ short sh[64 * 136];    // H chunk  [px][nl]
    __shared__ float sls[512], slt[512];
    int tid = threadIdx.x;
    int P0  = blockIdx.x * 64;

    // stage 64 px x 128 ch = 8192 shorts = 1024 uint4 copies
    #pragma unroll
    for (int it = 0; it < 4; ++it) {
        int idx = it * 256 + tid;            // 0..1023
        int row = idx >> 4, ch = idx & 15;
        *(uint4*)&sx[row * 136 + ch * 8] =
            *(const uint4*)&invb[(size_t)(P0 + row) * 128 + ch * 8];
    }
    sls[tid] = s1[tid]; sls[tid + 256] = s1[tid + 256];
    slt[tid] = t1[tid]; slt[tid + 256] = t1[tid + 256];
    __syncthreads();

    int lane = tid & 63, wv = tid >> 6;
    int ln15 = lane & 15, quad = lane >> 4;

    // per-lane LN stats for the 4 pixels this lane holds in phase-1 D cols
    float mu_r[4], rs_r[4];
    #pragma unroll
    for (int tn = 0; tn < 4; ++tn) {
        int p = P0 + tn * 16 + ln15;
        float m = ssum[p] * (1.f / 128.f);
        float v = ssq[p] * (1.f / 128.f) - m * m;
        mu_r[tn] = m; rs_r[tn] = rsqrtf(v + 1e-6f);
    }

    f32x4 acc2[4][2];
    #pragma unroll
    for (int i = 0; i < 4; ++i)
        #pragma unroll
        for (int j = 0; j < 2; ++j) acc2[i][j] = (f32x4)0.f;

    for (int j = 0; j < 4; ++j) {
        // ---- phase 1: H chunk [128 n x 64 px]; wave wv owns n-rows wv*32..+32
        f32x4 acc1[2][4];
        #pragma unroll
        for (int tm = 0; tm < 2; ++tm)
            #pragma unroll
            for (int tn = 0; tn < 4; ++tn) acc1[tm][tn] = (f32x4)0.f;
        #pragma unroll
        for (int kc = 0; kc < 128; kc += 32) {
            short8 af[2], bf[4];
            #pragma unroll
            for (int tm = 0; tm < 2; ++tm)
                af[tm] = *(const short8*)&lw1b[(size_t)(j * 128 + wv * 32 + tm * 16 + ln15) * 128 + kc + quad * 8];
            #pragma unroll
            for (int tn = 0; tn < 4; ++tn)
                bf[tn] = *(const short8*)&sx[(tn * 16 + ln15) * 136 + kc + quad * 8];
            #pragma unroll
            for (int tm = 0; tm < 2; ++tm)
                #pragma unroll
                for (int tn = 0; tn < 4; ++tn)
                    acc1[tm][tn] = __builtin_amdgcn_mfma_f32_16x16x32_bf16(af[tm], bf[tn], acc1[tm][tn], 0, 0, 0);
        }
        // LN + GELU epilogue -> sh  (lane: px = tn*16+ln15; rows nl = wv*32+tm*16+quad*4)
        #pragma unroll
        for (int tn = 0; tn < 4; ++tn) {
            int px = tn * 16 + ln15;
            #pragma unroll
            for (int tm = 0; tm < 2; ++tm) {
                int nl = wv * 32 + tm * 16 + quad * 4;
                int n  = j * 128 + nl;
                float g0 = gelu_t(rs_r[tn] * (acc1[tm][tn][0] - mu_r[tn] * sls[n + 0]) + slt[n + 0]);
                float g1 = gelu_t(rs_r[tn] * (acc1[tm][tn][1] - mu_r[tn] * sls[n + 1]) + slt[n + 1]);
                float g2 = gelu_t(rs_r[tn] * (acc1[tm][tn][2] - mu_r[tn] * sls[n + 2]) + slt[n + 2]);
                float g3 = gelu_t(rs_r[tn] * (acc1[tm][tn][3] - mu_r[tn] * sls[n + 3]) + slt[n + 3]);
                uint2 pk;
                pk.x = f2b(g0) | (f2b(g1) << 16);
                pk.y = f2b(g2) | (f2b(g3) << 16);
                *(uint2*)&sh[px * 136 + nl] = pk;
            }
        }
        __syncthreads();   // H complete (cross-wave reads next)
        // ---- phase 2: acc2[64 px x 128 c] += H . w2chunk^T; wave wv owns c wv*32..+32
        #pragma unroll
        for (int kc = 0; kc < 128; kc += 32) {
            short8 af[4], bf[2];
            #pragma unroll
            for (int tm = 0; tm < 4; ++tm)
                af[tm] = *(const short8*)&sh[(tm * 16 + ln15) * 136 + kc + quad * 8];
            #pragma unroll
            for (int tn = 0; tn < 2; ++tn)
                bf[tn] = *(const short8*)&w2b[(size_t)(wv * 32 + tn * 16 + ln15) * 512 + j * 128 + kc + quad * 8];
            #pragma unroll
            for (int tm = 0; tm < 4; ++tm)
                #pragma unroll
                for (int tn = 0; tn < 2; ++tn)
                    acc2[tm][tn] = __builtin_amdgcn_mfma_f32_16x16x32_bf16(af[tm], bf[tn], acc2[tm][tn], 0, 0, 0);
        }
        __syncthreads();   // before next chunk rewrites sh
    }

    // final epilogue: +b2 +residual, fp32 channels-first, full-line float4 stores
    int b = P0 / HW, p0i = P0 - b * HW;
    #pragma unroll
    for (int tm = 0; tm < 4; ++tm) {
        int p = p0i + tm * 16 + quad * 4;
        #pragma unroll
        for (int tn = 0; tn < 2; ++tn) {
            int c = wv * 32 + tn * 16 + ln15;
            size_t base = ((size_t)b * CIN + c) * HW + p;
            float bj = b2[c];
            float4 rv = *(const float4*)&xres[base];
            float4 ov = make_float4(acc2[tm][tn][0] + bj + rv.x,
                                    acc2[tm][tn][1] + bj + rv.y,
                                    acc2[tm][tn][2] + bj + rv.z,
                                    acc2[tm][tn][3] + bj + rv.w);
            *(float4*)&outp[base] = ov;
        }
    }
}

extern "C" void kernel_launch(void* const* d_in, const int* in_sizes, int n_in,
                              void* d_out, int out_size, void* d_ws, size_t ws_size,
                              hipStream_t stream) {
    const float* x       = (const float*)d_in[0];
    const float* conv1_w = (const float*)d_in[1];
    const float* conv1_b = (const float*)d_in[2];
    const float* bn_g    = (const float*)d_in[3];
    const float* bn_b    = (const float*)d_in[4];
    const float* bn_m    = (const float*)d_in[5];
    const float* bn_v    = (const float*)d_in[6];
    const float* conv2_w = (const float*)d_in[7];
    const float* conv2_b = (const float*)d_in[8];
    const float* ln_w    = (const float*)d_in[9];
    const float* ln_b    = (const float*)d_in[10];
    const float* w1      = (const float*)d_in[11];
    const float* b1      = (const float*)d_in[12];
    const float* w2      = (const float*)d_in[13];
    const float* b2      = (const float*)d_in[14];
    float* out = (float*)d_out;

    float* F = (float*)d_ws;
    float* ssum = F;                 // 25088
    float* ssq  = F + 25088;         // 25088
    float* sc1  = F + 50176;         // 32
    float* sh1  = F + 50208;         // 32
    float* s1   = F + 50240;         // 512
    float* t1   = F + 50752;         // 512
    ushort_t* S    = (ushort_t*)(F + 51264);
    ushort_t* wgtT = S;                       // 392*25088 = 9,834,496
    ushort_t* invb = S + 9834496;             // 25088*128 = 3,211,264
    ushort_t* c1b  = invb + 3211264;          // 4096
    ushort_t* c2b  = c1b + 4096;              // 12800 (400x32, padded)
    ushort_t* lw1b = c2b + 12800;             // 65536
    ushort_t* w2b  = lw1b + 65536;            // 65536

    k_prep <<<256, 256, 0, stream>>>(conv1_w, conv1_b, bn_g, bn_b, bn_m, bn_v,
                                     conv2_w, ln_w, w1, w2, c1b, c2b, lw1b, w2b, sc1, sh1);
    k_prep2<<<1, 512, 0, stream>>>(w1, ln_w, ln_b, b1, s1, t1);
    k_dw   <<<392, 256, 0, stream>>>(x, (const short*)c1b, (const short*)c2b,
                                     sc1, sh1, conv2_b, wgtT);
    k_inv  <<<392, 256, 0, stream>>>(x, wgtT, invb);
    k_stats<<<98, 256, 0, stream>>>(invb, ssum, ssq);
    k_mlp  <<<392, 256, 0, stream>>>(invb, lw1b, w2b, ssum, ssq, s1, t1, b2, x, out);
}

// Round 10
// 149.938 us; speedup vs baseline: 1.5481x; 1.1527x over previous
//
#include <hip/hip_runtime.h>
#include <hip/hip_bf16.h>
#include <math.h>

#define HW    3136
#define WIMG  56
#define NPIX  25088   // 8 * 3136
#define CIN   128
#define RED   32
#define NGROUP 8
#define GCH   16
#define KKK   49

typedef __attribute__((ext_vector_type(8))) short short8;
typedef __attribute__((ext_vector_type(4))) float f32x4;
typedef unsigned short ushort_t;

static __device__ __forceinline__ unsigned int f2b(float f) {
    union { __hip_bfloat16 b; unsigned short u; } cv;
    cv.b = __float2bfloat16(f);
    return (unsigned int)cv.u;
}

// tanh-form GELU (validated rounds 7-9: absmax 0.031)
static __device__ __forceinline__ float gelu_t(float h) {
    float z = h * fmaf(0.0356774081f, h * h, 0.7978845608f);
    float e = __expf(-2.f * z);
    return __fdividef(h, 1.f + e);
}

// ---------------- k_prep: weight conversions ----------------
__global__ __launch_bounds__(256) void k_prep(const float* __restrict__ conv1_w,
    const float* __restrict__ conv1_b, const float* __restrict__ bn_g,
    const float* __restrict__ bn_b, const float* __restrict__ bn_m,
    const float* __restrict__ bn_v, const float* __restrict__ conv2_w,
    const float* __restrict__ ln_w, const float* __restrict__ w1,
    const float* __restrict__ w2,
    ushort_t* __restrict__ c1b, ushort_t* __restrict__ c2b,
    ushort_t* __restrict__ lw1b, ushort_t* __restrict__ w2b,
    float* __restrict__ sc1, float* __restrict__ sh1)
{
    int id = blockIdx.x * 256 + threadIdx.x;     // 0..65535
    w2b[id] = (ushort_t)f2b(w2[id]);
    int c = id & 127;
    lw1b[id] = (ushort_t)f2b(w1[id] * ln_w[c]);
    if (id < 4096)  c1b[id] = (ushort_t)f2b(conv1_w[id]);
    if (id < 12800) c2b[id] = (id < 12544) ? (ushort_t)f2b(conv2_w[id]) : (ushort_t)0;
    if (id < 32) {
        float sc = bn_g[id] * rsqrtf(bn_v[id] + 1e-5f);
        sc1[id] = sc;
        sh1[id] = (conv1_b[id] - bn_m[id]) * sc + bn_b[id];
    }
}

// s1[n] = sum_c ln_w[c]*w1[n,c]; t1[n] = sum_c ln_b[c]*w1[n,c] + b1[n]
__global__ void k_prep2(const float* __restrict__ w1, const float* __restrict__ ln_w,
    const float* __restrict__ ln_b, const float* __restrict__ b1,
    float* __restrict__ s1, float* __restrict__ t1)
{
    int n = threadIdx.x;   // 512
    const float* wr = w1 + (size_t)n * 128;
    float s = 0.f, t = 0.f;
    #pragma unroll 8
    for (int c = 0; c < 128; ++c) { float w = wr[c]; s += ln_w[c] * w; t += ln_b[c] * w; }
    s1[n] = s; t1[n] = t + b1[n];
}

// ---------------- k_mega: conv1+BN+ReLU+conv2 -> involution -> LN -> MLP -> +res ----------------
// block = 64 pixels, grid 392. LDS phase overlay (79,936 B total -> 2 blocks/CU):
//   [0      , 53312) swg[392][68] bf16 (phase A out / B in)  == sh[64][136] (phase C)
//   [53312  , 70720) sx [64][136] bf16 (A: x tile; B out / C in: inv tile)
//   [70720  , 79936) st [64][40] bf16 (A)  ==  sred/sred2[64][17] f32 + smu/srs[64] (B/C)
__global__ __launch_bounds__(256) void k_mega(const float* __restrict__ x,
    const short* __restrict__ c1b, const short* __restrict__ c2b,
    const float* __restrict__ sc1, const float* __restrict__ sh1,
    const float* __restrict__ c2bias,
    const ushort_t* __restrict__ lw1b, const ushort_t* __restrict__ w2b,
    const float* __restrict__ s1, const float* __restrict__ t1,
    const float* __restrict__ b2, float* __restrict__ outp)
{
    __shared__ __align__(16) char smem[79936];
    short* swg  = (short*)smem;                    // [392][68]
    short* sh   = (short*)smem;                    // overlay of swg, [64][136]
    short* sx   = (short*)smem + 26656;            // [64][136]
    short* st   = (short*)(smem + 70720);          // [64][40] (phase A only)
    float* sred  = (float*)(smem + 70720);         // [64][17] (phase B+)
    float* sred2 = sred + 1088;
    float* smu   = sred2 + 1088;                   // [64]
    float* srs   = smu + 64;                       // [64]

    int tid  = threadIdx.x;
    int P0   = blockIdx.x * 64;
    int b    = P0 / HW;
    int p0i  = P0 - b * HW;
    int lane = tid & 63, wv = tid >> 6;
    int ln15 = lane & 15, quad = lane >> 4;

    // ======== Phase A0: stage x -> sx (bf16 [px][c], stride 136) ========
    const float* xb = x + (size_t)b * CIN * HW + p0i;
    #pragma unroll
    for (int it = 0; it < 32; ++it) {
        int idx = it * 256 + tid;
        int c = idx >> 6, pp = idx & 63;
        sx[pp * 136 + c] = (short)f2b(xb[(size_t)c * HW + pp]);
    }
    __syncthreads();

    // ======== Phase A1: conv1 + BN + ReLU -> st (wave-private rows) ========
    f32x4 acc1c[2] = {(f32x4)0.f, (f32x4)0.f};
    #pragma unroll
    for (int kc = 0; kc < 128; kc += 32) {
        short8 af = *(const short8*)&sx[(wv * 16 + ln15) * 136 + kc + quad * 8];
        #pragma unroll
        for (int nt = 0; nt < 2; ++nt) {
            short8 bf = *(const short8*)&c1b[(size_t)(nt * 16 + ln15) * 128 + kc + quad * 8];
            acc1c[nt] = __builtin_amdgcn_mfma_f32_16x16x32_bf16(af, bf, acc1c[nt], 0, 0, 0);
        }
    }
    #pragma unroll
    for (int nt = 0; nt < 2; ++nt) {
        int o = nt * 16 + ln15;
        float sc = sc1[o], shv = sh1[o];
        #pragma unroll
        for (int r = 0; r < 4; ++r) {
            float tv = fmaxf(acc1c[nt][r] * sc + shv, 0.f);
            st[(wv * 16 + quad * 4 + r) * 40 + o] = (short)f2b(tv);
        }
    }
    // ======== Phase A2: conv2 -> swg (LDS) ========
    short8 af2 = *(const short8*)&st[(wv * 16 + ln15) * 40 + quad * 8];
    f32x4 zc = (f32x4)0.f;
    #pragma unroll
    for (int nt = 0; nt < 25; ++nt) {
        int gk = nt * 16 + ln15;
        short8 bf2 = *(const short8*)&c2b[(size_t)gk * 32 + quad * 8];
        f32x4 a2 = __builtin_amdgcn_mfma_f32_16x16x32_bf16(af2, bf2, zc, 0, 0, 0);
        if (gk < 392) {
            float bj = c2bias[gk];
            uint2 pk;
            pk.x = f2b(a2[0] + bj) | (f2b(a2[1] + bj) << 16);
            pk.y = f2b(a2[2] + bj) | (f2b(a2[3] + bj) << 16);
            *(uint2*)&swg[gk * 68 + wv * 16 + quad * 4] = pk;
        }
    }
    __syncthreads();   // swg complete; sx (x-tile) free to overwrite

    // ======== Phase B: involution gather; inv -> sx; LN partials -> sred ========
    {
        int q   = tid & 15;          // px quad
        int gy  = tid >> 4;          // 0..15
        int g   = gy >> 1;
        int sub = gy & 1;
        int pl0 = q * 4;
        int p   = p0i + pl0;
        int prow = p / WIMG;
        int pcol = p - prow * WIMG;  // multiple of 4 (4 | 56 -> quad never straddles a row)
        const float* xc = x + ((size_t)b * CIN + g * GCH + sub * 8) * HW;
        float acc[4][8];
        #pragma unroll
        for (int i = 0; i < 4; ++i)
            #pragma unroll
            for (int c = 0; c < 8; ++c) acc[i][c] = 0.f;
        bool c_lo = (pcol >= 4);
        bool c_hi = (pcol <= 48);
        #pragma unroll
        for (int dy = -3; dy <= 3; ++dy) {
            int grow = prow + dy;
            if (grow < 0 || grow >= WIMG) continue;
            float wkf[7][4];
            #pragma unroll
            for (int dx = 0; dx < 7; ++dx) {
                int gk = g * KKK + (dy + 3) * 7 + dx;
                uint2 wld = *(const uint2*)&swg[gk * 68 + pl0];
                wkf[dx][0] = __uint_as_float(wld.x << 16);
                wkf[dx][1] = __uint_as_float(wld.x & 0xffff0000u);
                wkf[dx][2] = __uint_as_float(wld.y << 16);
                wkf[dx][3] = __uint_as_float(wld.y & 0xffff0000u);
            }
            const float* xrow = xc + grow * WIMG + pcol;
            #pragma unroll
            for (int c = 0; c < 8; ++c) {
                const float* xr = xrow + (size_t)c * HW;
                float4 v0 = c_lo ? *(const float4*)(xr - 4) : make_float4(0.f,0.f,0.f,0.f);
                float4 v1 = *(const float4*)(xr);
                float4 v2 = c_hi ? *(const float4*)(xr + 4) : make_float4(0.f,0.f,0.f,0.f);
                float vv[12] = {v0.x,v0.y,v0.z,v0.w, v1.x,v1.y,v1.z,v1.w, v2.x,v2.y,v2.z,v2.w};
                #pragma unroll
                for (int dx = 0; dx < 7; ++dx)
                    #pragma unroll
                    for (int i = 0; i < 4; ++i)
                        acc[i][c] += wkf[dx][i] * vv[i + dx + 1];
            }
        }
        #pragma unroll
        for (int i = 0; i < 4; ++i) {
            unsigned pk[4];
            float s = 0.f, s2 = 0.f;
            #pragma unroll
            for (int h = 0; h < 4; ++h)
                pk[h] = f2b(acc[i][2*h]) | (f2b(acc[i][2*h+1]) << 16);
            #pragma unroll
            for (int c = 0; c < 8; ++c) { s += acc[i][c]; s2 += acc[i][c] * acc[i][c]; }
            *(uint4*)&sx[(pl0 + i) * 136 + g * 16 + sub * 8] = make_uint4(pk[0],pk[1],pk[2],pk[3]);
            sred [(pl0 + i) * 17 + gy] = s;
            sred2[(pl0 + i) * 17 + gy] = s2;
        }
    }
    __syncthreads();   // inv tile + partials complete (also: swg dead from here)

    // ======== LN stats reduction ========
    if (tid < 64) {
        float s = 0.f, s2 = 0.f;
        #pragma unroll
        for (int gy = 0; gy < 16; ++gy) { s += sred[tid * 17 + gy]; s2 += sred2[tid * 17 + gy]; }
        float m = s * (1.f / 128.f);
        float v = s2 * (1.f / 128.f) - m * m;
        smu[tid] = m;
        srs[tid] = rsqrtf(v + 1e-6f);
    }
    __syncthreads();

    // ======== Phase C: MLP (4 hidden chunks of 128) ========
    float mu_r[4], rs_r[4];
    #pragma unroll
    for (int tn = 0; tn < 4; ++tn) {
        int px = tn * 16 + ln15;
        mu_r[tn] = smu[px];
        rs_r[tn] = srs[px];
    }

    f32x4 acc2[4][2];
    #pragma unroll
    for (int i = 0; i < 4; ++i)
        #pragma unroll
        for (int j = 0; j < 2; ++j) acc2[i][j] = (f32x4)0.f;

    for (int j = 0; j < 4; ++j) {
        f32x4 acc1[2][4];
        #pragma unroll
        for (int tm = 0; tm < 2; ++tm)
            #pragma unroll
            for (int tn = 0; tn < 4; ++tn) acc1[tm][tn] = (f32x4)0.f;
        #pragma unroll
        for (int kc = 0; kc < 128; kc += 32) {
            short8 af[2], bf[4];
            #pragma unroll
            for (int tm = 0; tm < 2; ++tm)
                af[tm] = *(const short8*)&lw1b[(size_t)(j * 128 + wv * 32 + tm * 16 + ln15) * 128 + kc + quad * 8];
            #pragma unroll
            for (int tn = 0; tn < 4; ++tn)
                bf[tn] = *(const short8*)&sx[(tn * 16 + ln15) * 136 + kc + quad * 8];
            #pragma unroll
            for (int tm = 0; tm < 2; ++tm)
                #pragma unroll
                for (int tn = 0; tn < 4; ++tn)
                    acc1[tm][tn] = __builtin_amdgcn_mfma_f32_16x16x32_bf16(af[tm], bf[tn], acc1[tm][tn], 0, 0, 0);
        }
        // LN + GELU -> sh (overlays swg; swg dead since barrier above)
        #pragma unroll
        for (int tm = 0; tm < 2; ++tm) {
            int nl = wv * 32 + tm * 16 + quad * 4;
            int n  = j * 128 + nl;
            float4 s14 = *(const float4*)&s1[n];
            float4 t14 = *(const float4*)&t1[n];
            #pragma unroll
            for (int tn = 0; tn < 4; ++tn) {
                int px = tn * 16 + ln15;
                float g0 = gelu_t(rs_r[tn] * (acc1[tm][tn][0] - mu_r[tn] * s14.x) + t14.x);
                float g1 = gelu_t(rs_r[tn] * (acc1[tm][tn][1] - mu_r[tn] * s14.y) + t14.y);
                float g2 = gelu_t(rs_r[tn] * (acc1[tm][tn][2] - mu_r[tn] * s14.z) + t14.z);
                float g3 = gelu_t(rs_r[tn] * (acc1[tm][tn][3] - mu_r[tn] * s14.w) + t14.w);
                uint2 pk;
                pk.x = f2b(g0) | (f2b(g1) << 16);
                pk.y = f2b(g2) | (f2b(g3) << 16);
                *(uint2*)&sh[px * 136 + nl] = pk;
            }
        }
        __syncthreads();   // H chunk complete
        #pragma unroll
        for (int kc = 0; kc < 128; kc += 32) {
            short8 af[4], bf[2];
            #pragma unroll
            for (int tm = 0; tm < 4; ++tm)
                af[tm] = *(const short8*)&sh[(tm * 16 + ln15) * 136 + kc + quad * 8];
            #pragma unroll
            for (int tn = 0; tn < 2; ++tn)
                bf[tn] = *(const short8*)&w2b[(size_t)(wv * 32 + tn * 16 + ln15) * 512 + j * 128 + kc + quad * 8];
            #pragma unroll
            for (int tm = 0; tm < 4; ++tm)
                #pragma unroll
                for (int tn = 0; tn < 2; ++tn)
                    acc2[tm][tn] = __builtin_amdgcn_mfma_f32_16x16x32_bf16(af[tm], bf[tn], acc2[tm][tn], 0, 0, 0);
        }
        __syncthreads();   // before next chunk rewrites sh
    }

    // ======== final epilogue: +b2 +residual, fp32 channels-first float4 ========
    #pragma unroll
    for (int tm = 0; tm < 4; ++tm) {
        int p = p0i + tm * 16 + quad * 4;
        #pragma unroll
        for (int tn = 0; tn < 2; ++tn) {
            int c = wv * 32 + tn * 16 + ln15;
            size_t base = ((size_t)b * CIN + c) * HW + p;
            float bj = b2[c];
            float4 rv = *(const float4*)&x[base];
            float4 ov = make_float4(acc2[tm][tn][0] + bj + rv.x,
                                    acc2[tm][tn][1] + bj + rv.y,
                                    acc2[tm][tn][2] + bj + rv.z,
                                    acc2[tm][tn][3] + bj + rv.w);
            *(float4*)&outp[base] = ov;
        }
    }
}

extern "C" void kernel_launch(void* const* d_in, const int* in_sizes, int n_in,
                              void* d_out, int out_size, void* d_ws, size_t ws_size,
                              hipStream_t stream) {
    const float* x       = (const float*)d_in[0];
    const float* conv1_w = (const float*)d_in[1];
    const float* conv1_b = (const float*)d_in[2];
    const float* bn_g    = (const float*)d_in[3];
    const float* bn_b    = (const float*)d_in[4];
    const float* bn_m    = (const float*)d_in[5];
    const float* bn_v    = (const float*)d_in[6];
    const float* conv2_w = (const float*)d_in[7];
    const float* conv2_b = (const float*)d_in[8];
    const float* ln_w    = (const float*)d_in[9];
    const float* ln_b    = (const float*)d_in[10];
    const float* w1      = (const float*)d_in[11];
    const float* b1      = (const float*)d_in[12];
    const float* w2      = (const float*)d_in[13];
    const float* b2      = (const float*)d_in[14];
    float* out = (float*)d_out;

    float* F = (float*)d_ws;
    float* sc1  = F;                 // 32
    float* sh1  = F + 32;            // 32
    float* s1   = F + 64;            // 512
    float* t1   = F + 576;           // 512
    ushort_t* S    = (ushort_t*)(F + 1088);
    ushort_t* c1b  = S;              // 4096
    ushort_t* c2b  = c1b + 4096;     // 12800 (400x32, zero-padded)
    ushort_t* lw1b = c2b + 12800;    // 65536
    ushort_t* w2b  = lw1b + 65536;   // 65536

    k_prep <<<256, 256, 0, stream>>>(conv1_w, conv1_b, bn_g, bn_b, bn_m, bn_v,
                                     conv2_w, ln_w, w1, w2, c1b, c2b, lw1b, w2b, sc1, sh1);
    k_prep2<<<1, 512, 0, stream>>>(w1, ln_w, ln_b, b1, s1, t1);
    k_mega <<<392, 256, 0, stream>>>(x, (const short*)c1b, (const short*)c2b,
                                     sc1, sh1, conv2_b, lw1b, w2b, s1, t1, b2, out);
}